// Round 1
// 522.508 us; speedup vs baseline: 1.0134x; 1.0134x over previous
//
#include <hip/hip_runtime.h>
#include <cstdint>
#include <cstddef>

// ---------------------------------------------------------------------------
// Problem constants (FeaturePropagationModule)
// ---------------------------------------------------------------------------
#define BATCHES   16
#define NC_PER    1024
#define NF_PER    4096
#define NC_TOT    (BATCHES * NC_PER)     // 16384
#define NF_TOT    (BATCHES * NF_PER)     // 65536
#define C_IN      512
#define C_SKIP    256
#define D_IN      (C_IN + C_SKIP)        // 768
#define C_OUT     512
#define BN_EPS    1e-5f

typedef __bf16 bf16x8 __attribute__((ext_vector_type(8)));
typedef __bf16 bf16x4 __attribute__((ext_vector_type(4)));
typedef float  f32x4  __attribute__((ext_vector_type(4)));

static_assert(sizeof(__bf16) == 2, "bf16 size");

// ---------------------------------------------------------------------------
// Kernel 1: transpose fp32 weight [K,N] -> bf16 [N,K]
// ---------------------------------------------------------------------------
__global__ __launch_bounds__(256) void transpose_to_bf16(
    const float* __restrict__ W, __bf16* __restrict__ Wt, int K, int N) {
  int idx = blockIdx.x * 256 + threadIdx.x;
  if (idx >= K * N) return;
  int n = idx / K;
  int k = idx - n * K;
  Wt[idx] = (__bf16)W[k * N + n];
}

// ---------------------------------------------------------------------------
// Kernel 2a: per-batch 3-NN (segmented scan, 4 segments of 256 per point).
// Distances replicate the numpy-fp32 oracle BIT-EXACTLY (per-op __f*_rn,
// numpy association order); lexicographic merge == stable ascending scan.
// ---------------------------------------------------------------------------
__global__ __launch_bounds__(256) void knn_kernel(
    const float* __restrict__ pos,      // [NC_TOT, 3]
    const float* __restrict__ pos_skip, // [NF_TOT, 3]
    int4*  __restrict__ idx3,           // [NF_TOT]
    float4* __restrict__ w3)            // [NF_TOT]
{
  __shared__ float s_pos[NC_PER * 3];   // 12 KiB
  __shared__ float s_pc2[NC_PER];       // 4 KiB
  __shared__ float s_pd[4][64][3];      // 3 KiB
  __shared__ int   s_pi[4][64][3];      // 3 KiB

  const int tid   = threadIdx.x;
  const int bi    = blockIdx.x;         // 1024 blocks
  const int fbase = bi * 64;
  const int b     = fbase >> 12;        // / NF_PER
  const int cbase = b * NC_PER;

  for (int i = tid; i < NC_PER * 3; i += 256)
    s_pos[i] = pos[(size_t)cbase * 3 + i];
  __syncthreads();
  for (int j = tid; j < NC_PER; j += 256) {
    float cx = s_pos[j * 3 + 0], cy = s_pos[j * 3 + 1], cz = s_pos[j * 3 + 2];
    s_pc2[j] = __fadd_rn(__fadd_rn(__fmul_rn(cx, cx), __fmul_rn(cy, cy)),
                         __fmul_rn(cz, cz));
  }
  __syncthreads();

  const int p   = tid & 63;
  const int seg = tid >> 6;
  const int f   = fbase + p;
  const float px = pos_skip[f * 3 + 0];
  const float py = pos_skip[f * 3 + 1];
  const float pz = pos_skip[f * 3 + 2];
  const float pf2 = __fadd_rn(__fadd_rn(__fmul_rn(px, px), __fmul_rn(py, py)),
                              __fmul_rn(pz, pz));
  float b0 = 1e30f, b1 = 1e30f, b2 = 1e30f;
  int   i0 = 0,     i1 = 0,     i2 = 0;
  const int j0 = seg * 256;
#pragma unroll 4
  for (int jj = 0; jj < 256; ++jj) {
    const int j = j0 + jj;
    float cx = s_pos[j * 3 + 0], cy = s_pos[j * 3 + 1], cz = s_pos[j * 3 + 2];
    float dot = __fadd_rn(__fadd_rn(__fmul_rn(px, cx), __fmul_rn(py, cy)),
                          __fmul_rn(pz, cz));
    float d2 = __fsub_rn(__fadd_rn(pf2, s_pc2[j]), __fmul_rn(2.0f, dot));
    if (d2 < b2) {                       // strict < keeps earliest (lowest j)
      if (d2 < b1) {
        b2 = b1; i2 = i1;
        if (d2 < b0) { b1 = b0; i1 = i0; b0 = d2; i0 = j; }
        else         { b1 = d2; i1 = j; }
      } else { b2 = d2; i2 = j; }
    }
  }
  s_pd[seg][p][0] = b0; s_pd[seg][p][1] = b1; s_pd[seg][p][2] = b2;
  s_pi[seg][p][0] = i0; s_pi[seg][p][1] = i1; s_pi[seg][p][2] = i2;
  __syncthreads();

  if (tid < 64) {
    float m0 = 1e30f, m1 = 1e30f, m2 = 1e30f;
    int  mi0 = 0,    mi1 = 0,    mi2 = 0;
#pragma unroll
    for (int s = 0; s < 4; ++s)
#pragma unroll
      for (int k = 0; k < 3; ++k) {
        float d = s_pd[s][tid][k];
        int   i = s_pi[s][tid][k];
        if (d < m2 || (d == m2 && i < mi2)) {
          if (d < m1 || (d == m1 && i < mi1)) {
            m2 = m1; mi2 = mi1;
            if (d < m0 || (d == m0 && i < mi0)) {
              m1 = m0; mi1 = mi0; m0 = d; mi0 = i;
            } else { m1 = d; mi1 = i; }
          } else { m2 = d; mi2 = i; }
        }
      }
    float w0 = 1.0f / fmaxf(m0, 1e-16f);
    float w1 = 1.0f / fmaxf(m1, 1e-16f);
    float w2 = 1.0f / fmaxf(m2, 1e-16f);
    float inv = 1.0f / __fadd_rn(__fadd_rn(w0, w1), w2);
    const int fo = fbase + tid;
    idx3[fo] = make_int4(mi0, mi1, mi2, 0);
    w3[fo]   = make_float4(w0 * inv, w1 * inv, w2 * inv, 0.f);
  }
}

// ---------------------------------------------------------------------------
// Kernel 2b: gather + weighted sum + concat skip -> h0 bf16.
// One wave per fine point; XCD swizzle keeps each XCD's 2 x-slabs in its L2.
// ---------------------------------------------------------------------------
__global__ __launch_bounds__(256) void gather_interp(
    const float* __restrict__ x,        // [NC_TOT, C_IN]
    const float* __restrict__ x_skip,   // [NF_TOT, C_SKIP]
    const int4*  __restrict__ idx3,     // [NF_TOT]
    const float4* __restrict__ w3,      // [NF_TOT]
    __bf16* __restrict__ h0)            // [NF_TOT, D_IN]
{
  const int bi   = blockIdx.x;          // 16384 blocks
  const int xcd  = bi & 7;
  const int slot = bi >> 3;             // 0..2047
  const int batch = xcd * 2 + (slot >> 10);
  const int blk   = slot & 1023;
  const int wv = threadIdx.x >> 6, ln = threadIdx.x & 63;
  const int f = batch * NF_PER + blk * 4 + wv;
  const int cbase = batch * NC_PER;

  const int4   id = idx3[f];
  const float4 w  = w3[f];
  const float* x0 = x + (size_t)(cbase + id.x) * C_IN;
  const float* x1 = x + (size_t)(cbase + id.y) * C_IN;
  const float* x2 = x + (size_t)(cbase + id.z) * C_IN;
  __bf16* o = h0 + (size_t)f * D_IN;
  const int c0 = ln * 4;
#pragma unroll
  for (int it = 0; it < 2; ++it) {
    const int c = c0 + it * 256;
    float4 a0 = *(const float4*)(x0 + c);
    float4 a1 = *(const float4*)(x1 + c);
    float4 a2 = *(const float4*)(x2 + c);
    bf16x4 ov;
    ov[0] = (__bf16)(w.x * a0.x + w.y * a1.x + w.z * a2.x);
    ov[1] = (__bf16)(w.x * a0.y + w.y * a1.y + w.z * a2.y);
    ov[2] = (__bf16)(w.x * a0.z + w.y * a1.z + w.z * a2.z);
    ov[3] = (__bf16)(w.x * a0.w + w.y * a1.w + w.z * a2.w);
    *(bf16x4*)(o + c) = ov;
  }
  float4 s = *(const float4*)(x_skip + (size_t)f * C_SKIP + c0);
  bf16x4 sv;
  sv[0] = (__bf16)s.x; sv[1] = (__bf16)s.y;
  sv[2] = (__bf16)s.z; sv[3] = (__bf16)s.w;
  *(bf16x4*)(o + C_IN + c0) = sv;
}

// ---------------------------------------------------------------------------
// Kernel 3: bf16 MFMA GEMM + bias, with fused column stats written as
// NON-ATOMIC per-block partials (part1[mblk][1024]: [0,512)=sum,
// [512,1024)=sumsq; every slot written exactly once -> no zeroing, no
// contention). 128x128 tile, 4 waves (2x2 of 64x64), 16x16x32 bf16 MFMA,
// BK=32, global_load_lds width-16 staging (m97 recipe).
//
// R4 changes (latency-bound fix; kernel was at 22% MfmaUtil / 35% HBM /
// 20% occupancy = barrier-drain bound, with 2x A over-fetch):
//  1. XCD-chunked work map: linear grid 2048, work=(bid&7)*256+(bid>>3),
//     n fastest -> all 4 n-tiles of an A-panel + 64 consecutive m-panels
//     live on one XCD's L2 (A fetched once per panel instead of ~2x, and
//     loads become ~200cy L2 hits instead of ~900cy HBM misses).
//  2. Double-buffered LDS, stage-next-BEFORE-compute-current (minimum
//     2-phase T3 recipe): one __syncthreads per K-step; its implicit
//     vmcnt(0) drain now overlaps with the current tile's ds_read+MFMA.
// ---------------------------------------------------------------------------
template <int K, bool BF16OUT>
__global__ __launch_bounds__(256) void gemm_bt(
    const __bf16* __restrict__ A,    // [M, K]
    const __bf16* __restrict__ Bt,   // [512, K]
    const float*  __restrict__ bias, // [512]
    void* __restrict__ Cout,         // [M, 512] (bf16 or f32)
    float* __restrict__ part1)       // [512][1024] per-mblock partials
{
  __shared__ __align__(16) __bf16 As[2][128 * 32];
  __shared__ __align__(16) __bf16 Bs[2][128 * 32];
  __shared__ float s_red[2][4][16][2];   // [wn][tn][l16][sum/ss], 1 KiB

  const int tid  = threadIdx.x;
  const int wave = tid >> 6, lane = tid & 63;
  const int quad = lane >> 4, l16 = lane & 15;
  const int wm = wave >> 1, wn = wave & 1;

  // XCD-chunked bijective work mapping (2048 blocks, 2048 % 8 == 0).
  // HW round-robins consecutive blockIdx across the 8 XCDs; give XCD x the
  // contiguous work range [x*256, (x+1)*256), n-tile fastest within it.
  const int bid  = blockIdx.x;
  const int work = (bid & 7) * 256 + (bid >> 3);
  const int my   = work >> 2;           // m-tile 0..511
  const int nx   = work & 3;            // n-tile 0..3
  const int m0 = my * 128, n0 = nx * 128;

  f32x4 acc[4][4] = {};

  auto stage = [&](int buf, int k0) {
#pragma unroll
    for (int q = 0; q < 2; ++q) {
      const int chunk = q * 256 + wave * 64 + lane;  // 16B chunk id
      const int row = chunk >> 2;
      const int col = (chunk & 3) << 3;
      __builtin_amdgcn_global_load_lds(
          (const __attribute__((address_space(1))) unsigned int*)(A + (size_t)(m0 + row) * K + (k0 + col)),
          (__attribute__((address_space(3))) unsigned int*)(As[buf] + (q * 256 + wave * 64) * 8),
          16, 0, 0);
      __builtin_amdgcn_global_load_lds(
          (const __attribute__((address_space(1))) unsigned int*)(Bt + (size_t)(n0 + row) * K + (k0 + col)),
          (__attribute__((address_space(3))) unsigned int*)(Bs[buf] + (q * 256 + wave * 64) * 8),
          16, 0, 0);
    }
  };

  // prologue: stage tile 0, drain (implicit vmcnt(0) in __syncthreads)
  stage(0, 0);
  __syncthreads();

  int cur = 0;
  for (int k0 = 0; k0 < K; k0 += 32) {
    // issue next tile's loads into the other buffer BEFORE compute; their
    // latency overlaps the ds_read+MFMA below and is drained by the single
    // end-of-step barrier.
    if (k0 + 32 < K) stage(cur ^ 1, k0 + 32);

    bf16x8 af[4], bfv[4];
#pragma unroll
    for (int t = 0; t < 4; ++t) {
      af[t]  = *(const bf16x8*)&As[cur][(wm * 64 + t * 16 + l16) * 32 + quad * 8];
      bfv[t] = *(const bf16x8*)&Bs[cur][(wn * 64 + t * 16 + l16) * 32 + quad * 8];
    }
#pragma unroll
    for (int tm = 0; tm < 4; ++tm)
#pragma unroll
      for (int tn = 0; tn < 4; ++tn)
        acc[tm][tn] = __builtin_amdgcn_mfma_f32_16x16x32_bf16(
            af[tm], bfv[tn], acc[tm][tn], 0, 0, 0);

    __syncthreads();   // drains staged loads + separates buffer reuse
    cur ^= 1;
  }

  // epilogue: C/D layout (verified m89/m91): n = lane&15, m = quad*4 + r
  float sArr[4], ssArr[4];
#pragma unroll
  for (int tn = 0; tn < 4; ++tn) {
    const int n = n0 + wn * 64 + tn * 16 + l16;
    const float bv = bias[n];
    float s = 0.f, ss = 0.f;
#pragma unroll
    for (int tm = 0; tm < 4; ++tm) {
      const int mb = m0 + wm * 64 + tm * 16 + quad * 4;
#pragma unroll
      for (int r = 0; r < 4; ++r) {
        const float v = acc[tm][tn][r] + bv;
        s += v; ss += v * v;
        if constexpr (BF16OUT)
          ((__bf16*)Cout)[(size_t)(mb + r) * 512 + n] = (__bf16)v;
        else
          ((float*)Cout)[(size_t)(mb + r) * 512 + n] = v;
      }
    }
    // reduce the 4 quads (lanes l16, l16+16, l16+32, l16+48 share column n)
    s  += __shfl_down(s, 32);  s  += __shfl_down(s, 16);
    ss += __shfl_down(ss, 32); ss += __shfl_down(ss, 16);
    sArr[tn] = s; ssArr[tn] = ss;
  }
  // combine the two m-waves (wm=0/1) via LDS, then one coalesced store
  if (wm == 1 && quad == 0) {
#pragma unroll
    for (int tn = 0; tn < 4; ++tn) {
      s_red[wn][tn][l16][0] = sArr[tn];
      s_red[wn][tn][l16][1] = ssArr[tn];
    }
  }
  __syncthreads();
  if (wm == 0 && quad == 0) {
    float* row = part1 + (size_t)my * 1024;
#pragma unroll
    for (int tn = 0; tn < 4; ++tn) {
      const int n = n0 + wn * 64 + tn * 16 + l16;
      row[n]       = sArr[tn]  + s_red[wn][tn][l16][0];
      row[512 + n] = ssArr[tn] + s_red[wn][tn][l16][1];
    }
  }
}

// ---------------------------------------------------------------------------
// Stage A: fold part1[512][1024] -> part2[16][1024] (coalesced)
// ---------------------------------------------------------------------------
__global__ __launch_bounds__(256) void reduce_partials(
    const float* __restrict__ part1, float* __restrict__ part2) {
  const int rb = blockIdx.x;            // 16 blocks, 32 rows each
  const int t  = threadIdx.x;
#pragma unroll
  for (int k = 0; k < 4; ++k) {
    const int c = k * 256 + t;
    float acc = 0.f;
    const float* p = part1 + (size_t)rb * 32 * 1024 + c;
#pragma unroll 8
    for (int r = 0; r < 32; ++r) { acc += *p; p += 1024; }
    part2[rb * 1024 + c] = acc;
  }
}

// ab layout: [0,512) = scale a, [512,1024) = shift b:  y = a*h + b
__global__ void finalize_stats(const float* __restrict__ part2,
                               const float* __restrict__ g,
                               const float* __restrict__ be,
                               float* __restrict__ ab, float invM) {
  const int c = blockIdx.x * 256 + threadIdx.x;
  if (c < 512) {
    float s = 0.f, ss = 0.f;
#pragma unroll
    for (int r = 0; r < 16; ++r) {
      s  += part2[r * 1024 + c];
      ss += part2[r * 1024 + 512 + c];
    }
    float mean = s * invM;
    float var  = ss * invM - mean * mean;
    float a = g[c] * rsqrtf(var + BN_EPS);
    ab[c] = a;
    ab[512 + c] = be[c] - mean * a;
  }
}

// ---------------------------------------------------------------------------
// In-place BN+ReLU on bf16 h1
// ---------------------------------------------------------------------------
__global__ __launch_bounds__(256) void bnrelu_bf16(
    __bf16* __restrict__ H, const float* __restrict__ ab) {
  const size_t e = ((size_t)blockIdx.x * 256 + threadIdx.x) * 4;
  const int c = (int)(e & 511);
  bf16x4* p = (bf16x4*)(H + e);
  bf16x4 h = *p;
#pragma unroll
  for (int i = 0; i < 4; ++i) {
    float v = (float)h[i];
    v = fmaxf(fmaf(v, ab[c + i], ab[512 + c + i]), 0.f);
    h[i] = (__bf16)v;
  }
  *p = h;
}

// ---------------------------------------------------------------------------
// BN+ReLU: read bf16 h2, write f32 out
// ---------------------------------------------------------------------------
__global__ __launch_bounds__(256) void bnrelu_b2f(
    const __bf16* __restrict__ H, const float* __restrict__ ab,
    float* __restrict__ O) {
  const size_t e = ((size_t)blockIdx.x * 256 + threadIdx.x) * 4;
  const int c = (int)(e & 511);
  bf16x4 h = *(const bf16x4*)(H + e);
  float4 o;
  o.x = fmaxf(fmaf((float)h[0], ab[c + 0], ab[512 + c + 0]), 0.f);
  o.y = fmaxf(fmaf((float)h[1], ab[c + 1], ab[512 + c + 1]), 0.f);
  o.z = fmaxf(fmaf((float)h[2], ab[c + 2], ab[512 + c + 2]), 0.f);
  o.w = fmaxf(fmaf((float)h[3], ab[c + 3], ab[512 + c + 3]), 0.f);
  *(float4*)(O + e) = o;
}

// ---------------------------------------------------------------------------
// Tail: pos_skip copy + batch ids as float
// ---------------------------------------------------------------------------
__global__ __launch_bounds__(256) void tail_kernel(
    const float* __restrict__ pos_skip, float* __restrict__ out2) {
  const int i = blockIdx.x * 256 + threadIdx.x;   // 0 .. 262143
  if (i < NF_TOT * 3) {
    out2[i] = pos_skip[i];
  } else {
    const int f = i - NF_TOT * 3;
    out2[i] = (float)(f >> 12);                   // f / NF_PER
  }
}

// ---------------------------------------------------------------------------
// Launch
// ---------------------------------------------------------------------------
extern "C" void kernel_launch(void* const* d_in, const int* in_sizes, int n_in,
                              void* d_out, int out_size, void* d_ws, size_t ws_size,
                              hipStream_t stream) {
  (void)in_sizes; (void)n_in; (void)out_size; (void)ws_size;

  const float* x        = (const float*)d_in[0];
  const float* pos      = (const float*)d_in[1];
  const float* x_skip   = (const float*)d_in[3];
  const float* pos_skip = (const float*)d_in[4];
  const float* W1  = (const float*)d_in[6];
  const float* b1  = (const float*)d_in[7];
  const float* g1  = (const float*)d_in[8];
  const float* be1 = (const float*)d_in[9];
  const float* W2  = (const float*)d_in[10];
  const float* b2  = (const float*)d_in[11];
  const float* g2  = (const float*)d_in[12];
  const float* be2 = (const float*)d_in[13];
  float* out = (float*)d_out;

  char* ws = (char*)d_ws;
  // workspace layout (bytes). h2 aliases h0 (h0 dead after gemm1).
  // part1 reuses the idx3/w3 region (dead after gather_interp).
  __bf16* h0   = (__bf16*)(ws);                          // 100,663,296  h0 [65536,768]
  __bf16* h2   = (__bf16*)(ws);                          //  67,108,864  h2 [65536,512]
  __bf16* h1   = (__bf16*)(ws + 100663296ull);           //  67,108,864  h1 [65536,512]
  __bf16* W1t  = (__bf16*)(ws + 167772160ull);           //     786,432  [512,768]
  __bf16* W2t  = (__bf16*)(ws + 168558592ull);           //     524,288  [512,512]
  float*  ab1   = (float*)(ws + 169086976ull);           //       4,096
  float*  ab2   = (float*)(ws + 169095168ull);           //       4,096
  int4*   idx3  = (int4*)(ws + 169099264ull);            //   1,048,576  [65536]
  float4* w3    = (float4*)(ws + 170147840ull);          //   1,048,576  [65536]
  float*  part1 = (float*)(ws + 169099264ull);           //   2,097,152  aliases idx3+w3
  float*  part2 = (float*)(ws + 171196416ull);           //      65,536  [16][1024]

  // weights -> transposed bf16
  transpose_to_bf16<<<(D_IN * C_OUT + 255) / 256, 256, 0, stream>>>(W1, W1t, D_IN, C_OUT);
  transpose_to_bf16<<<(C_OUT * C_OUT + 255) / 256, 256, 0, stream>>>(W2, W2t, C_OUT, C_OUT);

  // knn (segmented) then gather+concat -> h0
  knn_kernel<<<NF_TOT / 64, 256, 0, stream>>>(pos, pos_skip, idx3, w3);
  gather_interp<<<NF_TOT / 4, 256, 0, stream>>>(x, x_skip, idx3, w3, h0);

  // layer 1: gemm (+fused partial stats) -> reduce -> bn -> in-place bn+relu
  gemm_bt<D_IN, true><<<2048, 256, 0, stream>>>(h0, W1t, b1, (void*)h1, part1);
  reduce_partials<<<16, 256, 0, stream>>>(part1, part2);
  finalize_stats<<<2, 256, 0, stream>>>(part2, g1, be1, ab1, 1.0f / (float)NF_TOT);
  bnrelu_bf16<<<(NF_TOT * 512 / 4) / 256, 256, 0, stream>>>(h1, ab1);

  // layer 2: gemm -> bf16 h2 (+fused partial stats) -> bn+relu -> f32 out
  gemm_bt<C_OUT, true><<<2048, 256, 0, stream>>>(h1, W2t, b2, (void*)h2, part1);
  reduce_partials<<<16, 256, 0, stream>>>(part1, part2);
  finalize_stats<<<2, 256, 0, stream>>>(part2, g2, be2, ab2, 1.0f / (float)NF_TOT);
  bnrelu_b2f<<<(NF_TOT * 512 / 4) / 256, 256, 0, stream>>>(h2, ab2, out);

  // pos_skip + batch_skip outputs
  tail_kernel<<<(NF_TOT * 3 + NF_TOT + 255) / 256, 256, 0, stream>>>(
      pos_skip, out + (size_t)NF_TOT * 512);
}

// Round 2
// 506.432 us; speedup vs baseline: 1.0456x; 1.0317x over previous
//
#include <hip/hip_runtime.h>
#include <cstdint>
#include <cstddef>

// ---------------------------------------------------------------------------
// Problem constants (FeaturePropagationModule)
// ---------------------------------------------------------------------------
#define BATCHES   16
#define NC_PER    1024
#define NF_PER    4096
#define NC_TOT    (BATCHES * NC_PER)     // 16384
#define NF_TOT    (BATCHES * NF_PER)     // 65536
#define C_IN      512
#define C_SKIP    256
#define D_IN      (C_IN + C_SKIP)        // 768
#define C_OUT     512
#define BN_EPS    1e-5f

typedef __bf16 bf16x8 __attribute__((ext_vector_type(8)));
typedef __bf16 bf16x4 __attribute__((ext_vector_type(4)));
typedef float  f32x4  __attribute__((ext_vector_type(4)));

static_assert(sizeof(__bf16) == 2, "bf16 size");

// ---------------------------------------------------------------------------
// Kernel 1: transpose fp32 weight [K,N] -> bf16 [N,K]
// ---------------------------------------------------------------------------
__global__ __launch_bounds__(256) void transpose_to_bf16(
    const float* __restrict__ W, __bf16* __restrict__ Wt, int K, int N) {
  int idx = blockIdx.x * 256 + threadIdx.x;
  if (idx >= K * N) return;
  int n = idx / K;
  int k = idx - n * K;
  Wt[idx] = (__bf16)W[k * N + n];
}

// ---------------------------------------------------------------------------
// Kernel 2a: per-batch 3-NN (segmented scan, 4 segments of 256 per point).
// Distances replicate the numpy-fp32 oracle BIT-EXACTLY (per-op __f*_rn,
// numpy association order); lexicographic merge == stable ascending scan.
// ---------------------------------------------------------------------------
__global__ __launch_bounds__(256) void knn_kernel(
    const float* __restrict__ pos,      // [NC_TOT, 3]
    const float* __restrict__ pos_skip, // [NF_TOT, 3]
    int4*  __restrict__ idx3,           // [NF_TOT]
    float4* __restrict__ w3)            // [NF_TOT]
{
  __shared__ float s_pos[NC_PER * 3];   // 12 KiB
  __shared__ float s_pc2[NC_PER];       // 4 KiB
  __shared__ float s_pd[4][64][3];      // 3 KiB
  __shared__ int   s_pi[4][64][3];      // 3 KiB

  const int tid   = threadIdx.x;
  const int bi    = blockIdx.x;         // 1024 blocks
  const int fbase = bi * 64;
  const int b     = fbase >> 12;        // / NF_PER
  const int cbase = b * NC_PER;

  for (int i = tid; i < NC_PER * 3; i += 256)
    s_pos[i] = pos[(size_t)cbase * 3 + i];
  __syncthreads();
  for (int j = tid; j < NC_PER; j += 256) {
    float cx = s_pos[j * 3 + 0], cy = s_pos[j * 3 + 1], cz = s_pos[j * 3 + 2];
    s_pc2[j] = __fadd_rn(__fadd_rn(__fmul_rn(cx, cx), __fmul_rn(cy, cy)),
                         __fmul_rn(cz, cz));
  }
  __syncthreads();

  const int p   = tid & 63;
  const int seg = tid >> 6;
  const int f   = fbase + p;
  const float px = pos_skip[f * 3 + 0];
  const float py = pos_skip[f * 3 + 1];
  const float pz = pos_skip[f * 3 + 2];
  const float pf2 = __fadd_rn(__fadd_rn(__fmul_rn(px, px), __fmul_rn(py, py)),
                              __fmul_rn(pz, pz));
  float b0 = 1e30f, b1 = 1e30f, b2 = 1e30f;
  int   i0 = 0,     i1 = 0,     i2 = 0;
  const int j0 = seg * 256;
#pragma unroll 4
  for (int jj = 0; jj < 256; ++jj) {
    const int j = j0 + jj;
    float cx = s_pos[j * 3 + 0], cy = s_pos[j * 3 + 1], cz = s_pos[j * 3 + 2];
    float dot = __fadd_rn(__fadd_rn(__fmul_rn(px, cx), __fmul_rn(py, cy)),
                          __fmul_rn(pz, cz));
    float d2 = __fsub_rn(__fadd_rn(pf2, s_pc2[j]), __fmul_rn(2.0f, dot));
    if (d2 < b2) {                       // strict < keeps earliest (lowest j)
      if (d2 < b1) {
        b2 = b1; i2 = i1;
        if (d2 < b0) { b1 = b0; i1 = i0; b0 = d2; i0 = j; }
        else         { b1 = d2; i1 = j; }
      } else { b2 = d2; i2 = j; }
    }
  }
  s_pd[seg][p][0] = b0; s_pd[seg][p][1] = b1; s_pd[seg][p][2] = b2;
  s_pi[seg][p][0] = i0; s_pi[seg][p][1] = i1; s_pi[seg][p][2] = i2;
  __syncthreads();

  if (tid < 64) {
    float m0 = 1e30f, m1 = 1e30f, m2 = 1e30f;
    int  mi0 = 0,    mi1 = 0,    mi2 = 0;
#pragma unroll
    for (int s = 0; s < 4; ++s)
#pragma unroll
      for (int k = 0; k < 3; ++k) {
        float d = s_pd[s][tid][k];
        int   i = s_pi[s][tid][k];
        if (d < m2 || (d == m2 && i < mi2)) {
          if (d < m1 || (d == m1 && i < mi1)) {
            m2 = m1; mi2 = mi1;
            if (d < m0 || (d == m0 && i < mi0)) {
              m1 = m0; mi1 = mi0; m0 = d; mi0 = i;
            } else { m1 = d; mi1 = i; }
          } else { m2 = d; mi2 = i; }
        }
      }
    float w0 = 1.0f / fmaxf(m0, 1e-16f);
    float w1 = 1.0f / fmaxf(m1, 1e-16f);
    float w2 = 1.0f / fmaxf(m2, 1e-16f);
    float inv = 1.0f / __fadd_rn(__fadd_rn(w0, w1), w2);
    const int fo = fbase + tid;
    idx3[fo] = make_int4(mi0, mi1, mi2, 0);
    w3[fo]   = make_float4(w0 * inv, w1 * inv, w2 * inv, 0.f);
  }
}

// ---------------------------------------------------------------------------
// Kernel 2b: gather + weighted sum + concat skip -> h0 bf16.
// One wave per fine point; XCD swizzle keeps each XCD's 2 x-slabs in its L2.
// ---------------------------------------------------------------------------
__global__ __launch_bounds__(256) void gather_interp(
    const float* __restrict__ x,        // [NC_TOT, C_IN]
    const float* __restrict__ x_skip,   // [NF_TOT, C_SKIP]
    const int4*  __restrict__ idx3,     // [NF_TOT]
    const float4* __restrict__ w3,      // [NF_TOT]
    __bf16* __restrict__ h0)            // [NF_TOT, D_IN]
{
  const int bi   = blockIdx.x;          // 16384 blocks
  const int xcd  = bi & 7;
  const int slot = bi >> 3;             // 0..2047
  const int batch = xcd * 2 + (slot >> 10);
  const int blk   = slot & 1023;
  const int wv = threadIdx.x >> 6, ln = threadIdx.x & 63;
  const int f = batch * NF_PER + blk * 4 + wv;
  const int cbase = batch * NC_PER;

  const int4   id = idx3[f];
  const float4 w  = w3[f];
  const float* x0 = x + (size_t)(cbase + id.x) * C_IN;
  const float* x1 = x + (size_t)(cbase + id.y) * C_IN;
  const float* x2 = x + (size_t)(cbase + id.z) * C_IN;
  __bf16* o = h0 + (size_t)f * D_IN;
  const int c0 = ln * 4;
#pragma unroll
  for (int it = 0; it < 2; ++it) {
    const int c = c0 + it * 256;
    float4 a0 = *(const float4*)(x0 + c);
    float4 a1 = *(const float4*)(x1 + c);
    float4 a2 = *(const float4*)(x2 + c);
    bf16x4 ov;
    ov[0] = (__bf16)(w.x * a0.x + w.y * a1.x + w.z * a2.x);
    ov[1] = (__bf16)(w.x * a0.y + w.y * a1.y + w.z * a2.y);
    ov[2] = (__bf16)(w.x * a0.z + w.y * a1.z + w.z * a2.z);
    ov[3] = (__bf16)(w.x * a0.w + w.y * a1.w + w.z * a2.w);
    *(bf16x4*)(o + c) = ov;
  }
  float4 s = *(const float4*)(x_skip + (size_t)f * C_SKIP + c0);
  bf16x4 sv;
  sv[0] = (__bf16)s.x; sv[1] = (__bf16)s.y;
  sv[2] = (__bf16)s.z; sv[3] = (__bf16)s.w;
  *(bf16x4*)(o + C_IN + c0) = sv;
}

// ---------------------------------------------------------------------------
// Kernel 3 (R5): 256x256-tile 8-phase bf16 MFMA GEMM (m201 template ported).
//  - 512 threads = 8 waves (2M x 4N); per-wave C = 128x64; acc[8][4] f32x4.
//  - BK=64, double-buffered LDS (2 x 64 KiB), K-tile t in buf[t&1].
//  - T2 swizzle: 16B-slot XOR (slot ^= row&7) applied on BOTH sides:
//    inverse-permuted global source addr for global_load_lds (LDS dest
//    stays linear, rule #21) + same XOR on ds_read addresses.
//  - T3+T4: 4 phases/K-tile (one C-quadrant x K=64 = 16 MFMA each), raw
//    s_barrier, counted `s_waitcnt vmcnt(4)` ONCE per K-tile (vmcnt(0)
//    only on the last tile). Stages of K-tile t+1 issue at phases 0/1
//    (8 loads/thread/K-tile): entering tile t -> 8 outstanding (t's data),
//    +4 staged -> 12, vmcnt(4) drains exactly t's 8.
//  - T5: s_setprio(1/0) around each MFMA cluster.
//  - T1: XCD-chunked bijective block map (512 blocks; XCD x gets 64
//    contiguous works = 32 m-tiles x both n-tiles -> A panel reused in L2).
//  - Fused per-block column sum/sumsq partials -> part1[256][1024].
// ---------------------------------------------------------------------------
template <int K, bool BF16OUT>
__global__ __launch_bounds__(512, 2) void gemm_bt(
    const __bf16* __restrict__ A,    // [M, K]
    const __bf16* __restrict__ Bt,   // [512, K]
    const float*  __restrict__ bias, // [512]
    void* __restrict__ Cout,         // [M, 512] (bf16 or f32)
    float* __restrict__ part1)       // [256][1024] per-mblock partials
{
  constexpr int NT = K / 64;                        // K-tiles (12 or 8)
  __shared__ __align__(16) __bf16 As[2 * 16384];    // [buf][half][128][64]
  __shared__ __align__(16) __bf16 Bs[2 * 16384];
  __shared__ float s_red[4][4][16][2];              // [wn][nf][l16][sum/ss]

  const int tid  = threadIdx.x;
  const int wave = tid >> 6, lane = tid & 63;
  const int quad = lane >> 4, l16 = lane & 15;
  const int wm = wave >> 2, wn = wave & 3;          // 2 x 4 wave grid

  // T1: XCD-chunked bijective work mapping (512 % 8 == 0).
  const int bid  = blockIdx.x;
  const int work = (bid & 7) * 64 + (bid >> 3);
  const int mt = work >> 1, nt = work & 1;
  const int m0 = mt * 256, n0 = nt * 256;

  // ---- staging geometry (T2 write side) -----------------------------------
  // chunk = q*512 + wave*64 + lane; row = chunk>>3; slot = lane&7.
  // LDS linear dest holds global k-slot (slot ^ (row&7)) -> pre-swizzle src.
  const int rowA = wave * 8 + (lane >> 3);               // + q*64
  const int kOff = ((lane & 7) ^ (lane >> 3)) * 8;       // elements
  const int ldsChunkBase = (wave * 64) * 8;              // elements, + q*4096

  auto stage_half = [&](const __bf16* __restrict__ src, int rowBase, int t,
                        __bf16* dst) {
#pragma unroll
    for (int q = 0; q < 2; ++q) {
      __builtin_amdgcn_global_load_lds(
          (const __attribute__((address_space(1))) unsigned int*)(
              src + (size_t)(rowBase + q * 64 + rowA) * K + t * 64 + kOff),
          (__attribute__((address_space(3))) unsigned int*)(
              dst + q * 4096 + ldsChunkBase),
          16, 0, 0);
    }
  };

  f32x4 acc[8][4] = {};
  const int swz  = (l16 & 7) << 3;        // T2 read-side XOR (elements)
  const int brow = (wn & 1) * 64;         // wave's row base inside its B half

  // ---- prologue: K-tile 0 -> buf 0 (8 loads/thread) -----------------------
  stage_half(A,  m0,       0, As);
  stage_half(Bt, n0,       0, Bs);
  stage_half(A,  m0 + 128, 0, As + 8192);
  stage_half(Bt, n0 + 128, 0, Bs + 8192);

  bf16x8 aA[4][2], bB[4][2];
#pragma unroll 2
  for (int t = 0; t < NT; ++t) {
    const int cur = t & 1;
    const __bf16* Ab = As + (cur * 2 + wm) * 8192;         // wave's A half
    const __bf16* Bb = Bs + (cur * 2 + (wn >> 1)) * 8192;  // wave's B half
    __bf16* Asn = As + (cur ^ 1) * 16384;
    __bf16* Bsn = Bs + (cur ^ 1) * 16384;

    // ========== phase 0 : (m-half 0) x (n-frags 0,1) ==========
    if (t + 1 < NT) {
      stage_half(A,  m0,       t + 1, Asn);
      stage_half(Bt, n0,       t + 1, Bsn);
      asm volatile("s_waitcnt vmcnt(4)" ::: "memory");   // T4: counted, not 0
    } else {
      asm volatile("s_waitcnt vmcnt(0)" ::: "memory");   // last tile drains
    }
    __builtin_amdgcn_sched_barrier(0);
    __builtin_amdgcn_s_barrier();
#pragma unroll
    for (int mf = 0; mf < 4; ++mf)
#pragma unroll
      for (int ks = 0; ks < 2; ++ks)
        aA[mf][ks] = *(const bf16x8*)(Ab + (mf * 16 + l16) * 64 +
                                      ((ks * 32 + quad * 8) ^ swz));
#pragma unroll
    for (int nf = 0; nf < 2; ++nf)
#pragma unroll
      for (int ks = 0; ks < 2; ++ks)
        bB[nf][ks] = *(const bf16x8*)(Bb + (brow + nf * 16 + l16) * 64 +
                                      ((ks * 32 + quad * 8) ^ swz));
    __builtin_amdgcn_s_setprio(1);
#pragma unroll
    for (int mf = 0; mf < 4; ++mf)
#pragma unroll
      for (int nf = 0; nf < 2; ++nf)
#pragma unroll
        for (int ks = 0; ks < 2; ++ks)
          acc[mf][nf] = __builtin_amdgcn_mfma_f32_16x16x32_bf16(
              aA[mf][ks], bB[nf][ks], acc[mf][nf], 0, 0, 0);
    __builtin_amdgcn_s_setprio(0);
    __builtin_amdgcn_s_barrier();

    // ========== phase 1 : (m-half 0) x (n-frags 2,3) ==========
    if (t + 1 < NT) {
      stage_half(A,  m0 + 128, t + 1, Asn + 8192);
      stage_half(Bt, n0 + 128, t + 1, Bsn + 8192);
    }
#pragma unroll
    for (int nf = 2; nf < 4; ++nf)
#pragma unroll
      for (int ks = 0; ks < 2; ++ks)
        bB[nf][ks] = *(const bf16x8*)(Bb + (brow + nf * 16 + l16) * 64 +
                                      ((ks * 32 + quad * 8) ^ swz));
    __builtin_amdgcn_s_setprio(1);
#pragma unroll
    for (int mf = 0; mf < 4; ++mf)
#pragma unroll
      for (int nf = 2; nf < 4; ++nf)
#pragma unroll
        for (int ks = 0; ks < 2; ++ks)
          acc[mf][nf] = __builtin_amdgcn_mfma_f32_16x16x32_bf16(
              aA[mf][ks], bB[nf][ks], acc[mf][nf], 0, 0, 0);
    __builtin_amdgcn_s_setprio(0);
    __builtin_amdgcn_s_barrier();

    // ========== phase 2 : (m-half 1) x (n-frags 0,1) ==========
#pragma unroll
    for (int mf = 0; mf < 4; ++mf)
#pragma unroll
      for (int ks = 0; ks < 2; ++ks)
        aA[mf][ks] = *(const bf16x8*)(Ab + (64 + mf * 16 + l16) * 64 +
                                      ((ks * 32 + quad * 8) ^ swz));
    __builtin_amdgcn_s_setprio(1);
#pragma unroll
    for (int mf = 0; mf < 4; ++mf)
#pragma unroll
      for (int nf = 0; nf < 2; ++nf)
#pragma unroll
        for (int ks = 0; ks < 2; ++ks)
          acc[4 + mf][nf] = __builtin_amdgcn_mfma_f32_16x16x32_bf16(
              aA[mf][ks], bB[nf][ks], acc[4 + mf][nf], 0, 0, 0);
    __builtin_amdgcn_s_setprio(0);
    __builtin_amdgcn_s_barrier();

    // ========== phase 3 : (m-half 1) x (n-frags 2,3) ==========
    __builtin_amdgcn_s_setprio(1);
#pragma unroll
    for (int mf = 0; mf < 4; ++mf)
#pragma unroll
      for (int nf = 2; nf < 4; ++nf)
#pragma unroll
        for (int ks = 0; ks < 2; ++ks)
          acc[4 + mf][nf] = __builtin_amdgcn_mfma_f32_16x16x32_bf16(
              aA[mf][ks], bB[nf][ks], acc[4 + mf][nf], 0, 0, 0);
    __builtin_amdgcn_s_setprio(0);
    __builtin_amdgcn_s_barrier();
  }

  // ---- epilogue: C/D layout (m89/m91): n = l16, m = quad*4 + r ------------
  float sArr[4], ssArr[4];
#pragma unroll
  for (int nf = 0; nf < 4; ++nf) {
    const int n = n0 + wn * 64 + nf * 16 + l16;
    const float bv = bias[n];
    float s = 0.f, ss = 0.f;
#pragma unroll
    for (int mf = 0; mf < 8; ++mf) {
      const int mb = m0 + wm * 128 + mf * 16 + quad * 4;
#pragma unroll
      for (int r = 0; r < 4; ++r) {
        const float v = acc[mf][nf][r] + bv;
        s += v; ss += v * v;
        if constexpr (BF16OUT)
          ((__bf16*)Cout)[(size_t)(mb + r) * 512 + n] = (__bf16)v;
        else
          ((float*)Cout)[(size_t)(mb + r) * 512 + n] = v;
      }
    }
    // reduce the 4 quads (lanes l16, +16, +32, +48 share column n)
    s  += __shfl_down(s, 32);  s  += __shfl_down(s, 16);
    ss += __shfl_down(ss, 32); ss += __shfl_down(ss, 16);
    sArr[nf] = s; ssArr[nf] = ss;
  }
  // combine the two m-waves (wm=0/1) via LDS, then one coalesced store.
  // raw barrier + lgkm drain (avoid __syncthreads' vmcnt(0) store drain).
  if (wm == 1 && quad == 0) {
#pragma unroll
    for (int nf = 0; nf < 4; ++nf) {
      s_red[wn][nf][l16][0] = sArr[nf];
      s_red[wn][nf][l16][1] = ssArr[nf];
    }
  }
  asm volatile("s_waitcnt lgkmcnt(0)" ::: "memory");
  __builtin_amdgcn_s_barrier();
  if (wm == 0 && quad == 0) {
    float* row = part1 + (size_t)mt * 1024;
#pragma unroll
    for (int nf = 0; nf < 4; ++nf) {
      const int n = n0 + wn * 64 + nf * 16 + l16;
      row[n]       = sArr[nf]  + s_red[wn][nf][l16][0];
      row[512 + n] = ssArr[nf] + s_red[wn][nf][l16][1];
    }
  }
}

// ---------------------------------------------------------------------------
// Stage A: fold part1[256][1024] -> part2[16][1024] (coalesced)
// ---------------------------------------------------------------------------
__global__ __launch_bounds__(256) void reduce_partials(
    const float* __restrict__ part1, float* __restrict__ part2) {
  const int rb = blockIdx.x;            // 16 blocks, 16 rows each
  const int t  = threadIdx.x;
#pragma unroll
  for (int k = 0; k < 4; ++k) {
    const int c = k * 256 + t;
    float acc = 0.f;
    const float* p = part1 + (size_t)rb * 16 * 1024 + c;
#pragma unroll
    for (int r = 0; r < 16; ++r) { acc += *p; p += 1024; }
    part2[rb * 1024 + c] = acc;
  }
}

// ab layout: [0,512) = scale a, [512,1024) = shift b:  y = a*h + b
__global__ void finalize_stats(const float* __restrict__ part2,
                               const float* __restrict__ g,
                               const float* __restrict__ be,
                               float* __restrict__ ab, float invM) {
  const int c = blockIdx.x * 256 + threadIdx.x;
  if (c < 512) {
    float s = 0.f, ss = 0.f;
#pragma unroll
    for (int r = 0; r < 16; ++r) {
      s  += part2[r * 1024 + c];
      ss += part2[r * 1024 + 512 + c];
    }
    float mean = s * invM;
    float var  = ss * invM - mean * mean;
    float a = g[c] * rsqrtf(var + BN_EPS);
    ab[c] = a;
    ab[512 + c] = be[c] - mean * a;
  }
}

// ---------------------------------------------------------------------------
// In-place BN+ReLU on bf16 h1
// ---------------------------------------------------------------------------
__global__ __launch_bounds__(256) void bnrelu_bf16(
    __bf16* __restrict__ H, const float* __restrict__ ab) {
  const size_t e = ((size_t)blockIdx.x * 256 + threadIdx.x) * 4;
  const int c = (int)(e & 511);
  bf16x4* p = (bf16x4*)(H + e);
  bf16x4 h = *p;
#pragma unroll
  for (int i = 0; i < 4; ++i) {
    float v = (float)h[i];
    v = fmaxf(fmaf(v, ab[c + i], ab[512 + c + i]), 0.f);
    h[i] = (__bf16)v;
  }
  *p = h;
}

// ---------------------------------------------------------------------------
// BN+ReLU: read bf16 h2, write f32 out
// ---------------------------------------------------------------------------
__global__ __launch_bounds__(256) void bnrelu_b2f(
    const __bf16* __restrict__ H, const float* __restrict__ ab,
    float* __restrict__ O) {
  const size_t e = ((size_t)blockIdx.x * 256 + threadIdx.x) * 4;
  const int c = (int)(e & 511);
  bf16x4 h = *(const bf16x4*)(H + e);
  float4 o;
  o.x = fmaxf(fmaf((float)h[0], ab[c + 0], ab[512 + c + 0]), 0.f);
  o.y = fmaxf(fmaf((float)h[1], ab[c + 1], ab[512 + c + 1]), 0.f);
  o.z = fmaxf(fmaf((float)h[2], ab[c + 2], ab[512 + c + 2]), 0.f);
  o.w = fmaxf(fmaf((float)h[3], ab[c + 3], ab[512 + c + 3]), 0.f);
  *(float4*)(O + e) = o;
}

// ---------------------------------------------------------------------------
// Tail: pos_skip copy + batch ids as float
// ---------------------------------------------------------------------------
__global__ __launch_bounds__(256) void tail_kernel(
    const float* __restrict__ pos_skip, float* __restrict__ out2) {
  const int i = blockIdx.x * 256 + threadIdx.x;   // 0 .. 262143
  if (i < NF_TOT * 3) {
    out2[i] = pos_skip[i];
  } else {
    const int f = i - NF_TOT * 3;
    out2[i] = (float)(f >> 12);                   // f / NF_PER
  }
}

// ---------------------------------------------------------------------------
// Launch
// ---------------------------------------------------------------------------
extern "C" void kernel_launch(void* const* d_in, const int* in_sizes, int n_in,
                              void* d_out, int out_size, void* d_ws, size_t ws_size,
                              hipStream_t stream) {
  (void)in_sizes; (void)n_in; (void)out_size; (void)ws_size;

  const float* x        = (const float*)d_in[0];
  const float* pos      = (const float*)d_in[1];
  const float* x_skip   = (const float*)d_in[3];
  const float* pos_skip = (const float*)d_in[4];
  const float* W1  = (const float*)d_in[6];
  const float* b1  = (const float*)d_in[7];
  const float* g1  = (const float*)d_in[8];
  const float* be1 = (const float*)d_in[9];
  const float* W2  = (const float*)d_in[10];
  const float* b2  = (const float*)d_in[11];
  const float* g2  = (const float*)d_in[12];
  const float* be2 = (const float*)d_in[13];
  float* out = (float*)d_out;

  char* ws = (char*)d_ws;
  // workspace layout (bytes). h2 aliases h0 (h0 dead after gemm1).
  // part1 reuses the idx3/w3 region (dead after gather_interp).
  __bf16* h0   = (__bf16*)(ws);                          // 100,663,296  h0 [65536,768]
  __bf16* h2   = (__bf16*)(ws);                          //  67,108,864  h2 [65536,512]
  __bf16* h1   = (__bf16*)(ws + 100663296ull);           //  67,108,864  h1 [65536,512]
  __bf16* W1t  = (__bf16*)(ws + 167772160ull);           //     786,432  [512,768]
  __bf16* W2t  = (__bf16*)(ws + 168558592ull);           //     524,288  [512,512]
  float*  ab1   = (float*)(ws + 169086976ull);           //       4,096
  float*  ab2   = (float*)(ws + 169095168ull);           //       4,096
  int4*   idx3  = (int4*)(ws + 169099264ull);            //   1,048,576  [65536]
  float4* w3    = (float4*)(ws + 170147840ull);          //   1,048,576  [65536]
  float*  part1 = (float*)(ws + 169099264ull);           //   1,048,576  aliases idx3
  float*  part2 = (float*)(ws + 171196416ull);           //      65,536  [16][1024]

  // weights -> transposed bf16
  transpose_to_bf16<<<(D_IN * C_OUT + 255) / 256, 256, 0, stream>>>(W1, W1t, D_IN, C_OUT);
  transpose_to_bf16<<<(C_OUT * C_OUT + 255) / 256, 256, 0, stream>>>(W2, W2t, C_OUT, C_OUT);

  // knn (segmented) then gather+concat -> h0
  knn_kernel<<<NF_TOT / 64, 256, 0, stream>>>(pos, pos_skip, idx3, w3);
  gather_interp<<<NF_TOT / 4, 256, 0, stream>>>(x, x_skip, idx3, w3, h0);

  // layer 1: gemm (+fused partial stats) -> reduce -> bn -> in-place bn+relu
  gemm_bt<D_IN, true><<<512, 512, 0, stream>>>(h0, W1t, b1, (void*)h1, part1);
  reduce_partials<<<16, 256, 0, stream>>>(part1, part2);
  finalize_stats<<<2, 256, 0, stream>>>(part2, g1, be1, ab1, 1.0f / (float)NF_TOT);
  bnrelu_bf16<<<(NF_TOT * 512 / 4) / 256, 256, 0, stream>>>(h1, ab1);

  // layer 2: gemm -> bf16 h2 (+fused partial stats) -> bn+relu -> f32 out
  gemm_bt<C_OUT, true><<<512, 512, 0, stream>>>(h1, W2t, b2, (void*)h2, part1);
  reduce_partials<<<16, 256, 0, stream>>>(part1, part2);
  finalize_stats<<<2, 256, 0, stream>>>(part2, g2, be2, ab2, 1.0f / (float)NF_TOT);
  bnrelu_b2f<<<(NF_TOT * 512 / 4) / 256, 256, 0, stream>>>(h2, ab2, out);

  // pos_skip + batch_skip outputs
  tail_kernel<<<(NF_TOT * 3 + NF_TOT + 255) / 256, 256, 0, stream>>>(
      pos_skip, out + (size_t)NF_TOT * 512);
}

// Round 3
// 471.999 us; speedup vs baseline: 1.1219x; 1.0730x over previous
//
#include <hip/hip_runtime.h>
#include <cstdint>
#include <cstddef>

// ---------------------------------------------------------------------------
// Problem constants (FeaturePropagationModule)
// ---------------------------------------------------------------------------
#define BATCHES   16
#define NC_PER    1024
#define NF_PER    4096
#define NC_TOT    (BATCHES * NC_PER)     // 16384
#define NF_TOT    (BATCHES * NF_PER)     // 65536
#define C_IN      512
#define C_SKIP    256
#define D_IN      (C_IN + C_SKIP)        // 768
#define C_OUT     512
#define BN_EPS    1e-5f

typedef __bf16 bf16x8 __attribute__((ext_vector_type(8)));
typedef __bf16 bf16x4 __attribute__((ext_vector_type(4)));
typedef float  f32x4  __attribute__((ext_vector_type(4)));

static_assert(sizeof(__bf16) == 2, "bf16 size");

// inline-asm 16B global load: issue point is pinned by surrounding volatile
// fences; completion is guaranteed ONLY by our manual counted vmcnt.
__device__ __forceinline__ bf16x8 load16(const __bf16* p) {
  f32x4 r;
  asm volatile("global_load_dwordx4 %0, %1, off" : "=v"(r) : "v"(p));
  union { f32x4 f; bf16x8 b; } u; u.f = r; return u.b;
}

// ---------------------------------------------------------------------------
// Kernel 1: both weight transposes fused. fp32 [K,N] -> bf16 [N,K]
// ---------------------------------------------------------------------------
__global__ __launch_bounds__(256) void transpose_both(
    const float* __restrict__ W1, const float* __restrict__ W2,
    __bf16* __restrict__ W1t, __bf16* __restrict__ W2t) {
  int idx = blockIdx.x * 256 + threadIdx.x;
  if (idx < D_IN * C_OUT) {                 // W1: K=768, N=512
    int n = idx / D_IN, k = idx - n * D_IN;
    W1t[idx] = (__bf16)W1[k * C_OUT + n];
  } else {
    idx -= D_IN * C_OUT;
    if (idx < C_OUT * C_OUT) {              // W2: K=512, N=512
      int n = idx >> 9, k = idx & 511;
      W2t[idx] = (__bf16)W2[k * C_OUT + n];
    }
  }
}

// ---------------------------------------------------------------------------
// Kernel 2a: per-batch 3-NN (segmented scan, 4 segments of 256 per point).
// Distances replicate the numpy-fp32 oracle BIT-EXACTLY (per-op __f*_rn,
// numpy association order); lexicographic merge == stable ascending scan.
// ---------------------------------------------------------------------------
__global__ __launch_bounds__(256) void knn_kernel(
    const float* __restrict__ pos,      // [NC_TOT, 3]
    const float* __restrict__ pos_skip, // [NF_TOT, 3]
    int4*  __restrict__ idx3,           // [NF_TOT]
    float4* __restrict__ w3)            // [NF_TOT]
{
  __shared__ float s_pos[NC_PER * 3];   // 12 KiB
  __shared__ float s_pc2[NC_PER];       // 4 KiB
  __shared__ float s_pd[4][64][3];      // 3 KiB
  __shared__ int   s_pi[4][64][3];      // 3 KiB

  const int tid   = threadIdx.x;
  const int bi    = blockIdx.x;         // 1024 blocks
  const int fbase = bi * 64;
  const int b     = fbase >> 12;        // / NF_PER
  const int cbase = b * NC_PER;

  for (int i = tid; i < NC_PER * 3; i += 256)
    s_pos[i] = pos[(size_t)cbase * 3 + i];
  __syncthreads();
  for (int j = tid; j < NC_PER; j += 256) {
    float cx = s_pos[j * 3 + 0], cy = s_pos[j * 3 + 1], cz = s_pos[j * 3 + 2];
    s_pc2[j] = __fadd_rn(__fadd_rn(__fmul_rn(cx, cx), __fmul_rn(cy, cy)),
                         __fmul_rn(cz, cz));
  }
  __syncthreads();

  const int p   = tid & 63;
  const int seg = tid >> 6;
  const int f   = fbase + p;
  const float px = pos_skip[f * 3 + 0];
  const float py = pos_skip[f * 3 + 1];
  const float pz = pos_skip[f * 3 + 2];
  const float pf2 = __fadd_rn(__fadd_rn(__fmul_rn(px, px), __fmul_rn(py, py)),
                              __fmul_rn(pz, pz));
  float b0 = 1e30f, b1 = 1e30f, b2 = 1e30f;
  int   i0 = 0,     i1 = 0,     i2 = 0;
  const int j0 = seg * 256;
#pragma unroll 4
  for (int jj = 0; jj < 256; ++jj) {
    const int j = j0 + jj;
    float cx = s_pos[j * 3 + 0], cy = s_pos[j * 3 + 1], cz = s_pos[j * 3 + 2];
    float dot = __fadd_rn(__fadd_rn(__fmul_rn(px, cx), __fmul_rn(py, cy)),
                          __fmul_rn(pz, cz));
    float d2 = __fsub_rn(__fadd_rn(pf2, s_pc2[j]), __fmul_rn(2.0f, dot));
    if (d2 < b2) {                       // strict < keeps earliest (lowest j)
      if (d2 < b1) {
        b2 = b1; i2 = i1;
        if (d2 < b0) { b1 = b0; i1 = i0; b0 = d2; i0 = j; }
        else         { b1 = d2; i1 = j; }
      } else { b2 = d2; i2 = j; }
    }
  }
  s_pd[seg][p][0] = b0; s_pd[seg][p][1] = b1; s_pd[seg][p][2] = b2;
  s_pi[seg][p][0] = i0; s_pi[seg][p][1] = i1; s_pi[seg][p][2] = i2;
  __syncthreads();

  if (tid < 64) {
    float m0 = 1e30f, m1 = 1e30f, m2 = 1e30f;
    int  mi0 = 0,    mi1 = 0,    mi2 = 0;
#pragma unroll
    for (int s = 0; s < 4; ++s)
#pragma unroll
      for (int k = 0; k < 3; ++k) {
        float d = s_pd[s][tid][k];
        int   i = s_pi[s][tid][k];
        if (d < m2 || (d == m2 && i < mi2)) {
          if (d < m1 || (d == m1 && i < mi1)) {
            m2 = m1; mi2 = mi1;
            if (d < m0 || (d == m0 && i < mi0)) {
              m1 = m0; mi1 = mi0; m0 = d; mi0 = i;
            } else { m1 = d; mi1 = i; }
          } else { m2 = d; mi2 = i; }
        }
      }
    float w0 = 1.0f / fmaxf(m0, 1e-16f);
    float w1 = 1.0f / fmaxf(m1, 1e-16f);
    float w2 = 1.0f / fmaxf(m2, 1e-16f);
    float inv = 1.0f / __fadd_rn(__fadd_rn(w0, w1), w2);
    const int fo = fbase + tid;
    idx3[fo] = make_int4(mi0, mi1, mi2, 0);
    w3[fo]   = make_float4(w0 * inv, w1 * inv, w2 * inv, 0.f);
  }
}

// ---------------------------------------------------------------------------
// Kernel 2b: gather + weighted sum + concat skip -> h0 bf16.
// One wave per fine point; XCD swizzle keeps each XCD's 2 x-slabs in its L2.
// ---------------------------------------------------------------------------
__global__ __launch_bounds__(256) void gather_interp(
    const float* __restrict__ x,        // [NC_TOT, C_IN]
    const float* __restrict__ x_skip,   // [NF_TOT, C_SKIP]
    const int4*  __restrict__ idx3,     // [NF_TOT]
    const float4* __restrict__ w3,      // [NF_TOT]
    __bf16* __restrict__ h0)            // [NF_TOT, D_IN]
{
  const int bi   = blockIdx.x;          // 16384 blocks
  const int xcd  = bi & 7;
  const int slot = bi >> 3;             // 0..2047
  const int batch = xcd * 2 + (slot >> 10);
  const int blk   = slot & 1023;
  const int wv = threadIdx.x >> 6, ln = threadIdx.x & 63;
  const int f = batch * NF_PER + blk * 4 + wv;
  const int cbase = batch * NC_PER;

  const int4   id = idx3[f];
  const float4 w  = w3[f];
  const float* x0 = x + (size_t)(cbase + id.x) * C_IN;
  const float* x1 = x + (size_t)(cbase + id.y) * C_IN;
  const float* x2 = x + (size_t)(cbase + id.z) * C_IN;
  __bf16* o = h0 + (size_t)f * D_IN;
  const int c0 = ln * 4;
#pragma unroll
  for (int it = 0; it < 2; ++it) {
    const int c = c0 + it * 256;
    float4 a0 = *(const float4*)(x0 + c);
    float4 a1 = *(const float4*)(x1 + c);
    float4 a2 = *(const float4*)(x2 + c);
    bf16x4 ov;
    ov[0] = (__bf16)(w.x * a0.x + w.y * a1.x + w.z * a2.x);
    ov[1] = (__bf16)(w.x * a0.y + w.y * a1.y + w.z * a2.y);
    ov[2] = (__bf16)(w.x * a0.z + w.y * a1.z + w.z * a2.z);
    ov[3] = (__bf16)(w.x * a0.w + w.y * a1.w + w.z * a2.w);
    *(bf16x4*)(o + c) = ov;
  }
  float4 s = *(const float4*)(x_skip + (size_t)f * C_SKIP + c0);
  bf16x4 sv;
  sv[0] = (__bf16)s.x; sv[1] = (__bf16)s.y;
  sv[2] = (__bf16)s.z; sv[3] = (__bf16)s.w;
  *(bf16x4*)(o + C_IN + c0) = sv;
}

// ---------------------------------------------------------------------------
// Kernel 3 (R6): 256x256 8-phase bf16 MFMA GEMM. K-loop identical to R5.
// R6 changes:
//  a) Coalesced C-store: repack the 256x256 bf16 C-tile through the dead
//     As/Bs LDS (quad-XOR swizzled, conflict-free) and store bf16x8/lane
//     (kills the 32B-segment write amplification: WRITE 127->~69 MB).
//  b) FUSE_BN (gemm2): A is reg-staged via inline-asm loads issued at
//     phase 0 (counted vmcnt: entry vmcnt(6), ph3 vmcnt(4) drains A),
//     BN1+ReLU applied from LDS-cached ab1, ds_write_b128 into the same
//     swizzled layout the DMA path produces. Eliminates the bnrelu_bf16
//     full-tensor pass.
// ---------------------------------------------------------------------------
template <int K, bool FUSE_BN>
__global__ __launch_bounds__(512, 2) void gemm_bt(
    const __bf16* __restrict__ A,    // [M, K]
    const __bf16* __restrict__ Bt,   // [512, K]
    const float*  __restrict__ bias, // [512]
    __bf16* __restrict__ Cout,       // [M, 512]
    float* __restrict__ part1,       // [256][1024] per-mblock partials
    const float* __restrict__ ab)    // [1024] BN a/b (FUSE_BN only)
{
  constexpr int NT = K / 64;                        // K-tiles (12 or 8)
  __shared__ __align__(16) __bf16 As[2 * 16384];    // [buf][half][128][64]
  __shared__ __align__(16) __bf16 Bs[2 * 16384];
  __shared__ float s_red[4][4][16][2];              // [wn][nf][l16][sum/ss]
  __shared__ float s_ab[1024];                      // BN coeffs (FUSE_BN)

  const int tid  = threadIdx.x;
  const int wave = tid >> 6, lane = tid & 63;
  const int quad = lane >> 4, l16 = lane & 15;
  const int wm = wave >> 2, wn = wave & 3;          // 2 x 4 wave grid

  // T1: XCD-chunked bijective work mapping (512 % 8 == 0).
  const int bid  = blockIdx.x;
  const int work = (bid & 7) * 64 + (bid >> 3);
  const int mt = work >> 1, nt = work & 1;
  const int m0 = mt * 256, n0 = nt * 256;

  // ---- staging geometry (T2 write side) -----------------------------------
  const int slot = lane & 7, rsub = lane >> 3;
  const int rowA = wave * 8 + rsub;                 // + q*64
  const int kSw  = (slot ^ rsub) * 8;               // swizzled k-off (elems)
  const int ldsChunkBase = (wave * 64) * 8;         // elems, + q*4096

  auto stage_half = [&](const __bf16* __restrict__ src, int rowBase, int t,
                        __bf16* dst) {
#pragma unroll
    for (int q = 0; q < 2; ++q) {
      __builtin_amdgcn_global_load_lds(
          (const __attribute__((address_space(1))) unsigned int*)(
              src + (size_t)(rowBase + q * 64 + rowA) * K + t * 64 + kSw),
          (__attribute__((address_space(3))) unsigned int*)(
              dst + q * 4096 + ldsChunkBase),
          16, 0, 0);
    }
  };

  bf16x8 ar[4];  // FUSE_BN: in-flight A tile (h*2+q)

  auto load_a_regs = [&](int tt) {
#pragma unroll
    for (int h = 0; h < 2; ++h)
#pragma unroll
      for (int q = 0; q < 2; ++q)
        ar[h * 2 + q] = load16(A + (size_t)(m0 + h * 128 + q * 64 + rowA) * K +
                               tt * 64 + slot * 8);
  };
  auto bn_write_A = [&](int tt, __bf16* dstbuf) {
    const int cb = tt * 64 + slot * 8;
    const float4 aL = *(const float4*)&s_ab[cb];
    const float4 aH = *(const float4*)&s_ab[cb + 4];
    const float4 bL = *(const float4*)&s_ab[512 + cb];
    const float4 bH = *(const float4*)&s_ab[512 + cb + 4];
#pragma unroll
    for (int i = 0; i < 4; ++i) {
      bf16x8 v = ar[i]; bf16x8 o;
      o[0] = (__bf16)fmaxf(fmaf((float)v[0], aL.x, bL.x), 0.f);
      o[1] = (__bf16)fmaxf(fmaf((float)v[1], aL.y, bL.y), 0.f);
      o[2] = (__bf16)fmaxf(fmaf((float)v[2], aL.z, bL.z), 0.f);
      o[3] = (__bf16)fmaxf(fmaf((float)v[3], aL.w, bL.w), 0.f);
      o[4] = (__bf16)fmaxf(fmaf((float)v[4], aH.x, bH.x), 0.f);
      o[5] = (__bf16)fmaxf(fmaf((float)v[5], aH.y, bH.y), 0.f);
      o[6] = (__bf16)fmaxf(fmaf((float)v[6], aH.z, bH.z), 0.f);
      o[7] = (__bf16)fmaxf(fmaf((float)v[7], aH.w, bH.w), 0.f);
      const int h = i >> 1, q = i & 1;
      *(bf16x8*)(dstbuf + h * 8192 + (size_t)(q * 64 + rowA) * 64 + kSw) = o;
    }
  };

  f32x4 acc[8][4] = {};
  const int swz  = (l16 & 7) << 3;        // T2 read-side XOR (elements)
  const int brow = (wn & 1) * 64;         // wave's row base inside its B half

  // ---- prologue: K-tile 0 -> buf 0 ----------------------------------------
  if constexpr (FUSE_BN) {
    for (int i = tid; i < 1024; i += 512) s_ab[i] = ab[i];
    load_a_regs(0);                       // 4 asm loads
    stage_half(Bt, n0,       0, Bs);      // 4 DMA
    stage_half(Bt, n0 + 128, 0, Bs + 8192);
    __syncthreads();                      // vmcnt(0)+lgkm; s_ab visible
    bn_write_A(0, As);
    asm volatile("s_waitcnt lgkmcnt(0)" ::: "memory");
    __builtin_amdgcn_sched_barrier(0);
    __builtin_amdgcn_s_barrier();
  } else {
    stage_half(A,  m0,       0, As);
    stage_half(Bt, n0,       0, Bs);
    stage_half(A,  m0 + 128, 0, As + 8192);
    stage_half(Bt, n0 + 128, 0, Bs + 8192);
  }

  bf16x8 aA[4][2], bB[4][2];
#pragma unroll 2
  for (int t = 0; t < NT; ++t) {
    const int cur = t & 1;
    const __bf16* Ab = As + (cur * 2 + wm) * 8192;         // wave's A half
    const __bf16* Bb = Bs + (cur * 2 + (wn >> 1)) * 8192;  // wave's B half
    __bf16* Asn = As + (cur ^ 1) * 16384;
    __bf16* Bsn = Bs + (cur ^ 1) * 16384;

    // ========== phase 0 : (m-half 0) x (n-frags 0,1) ==========
    if (t + 1 < NT) {
      if constexpr (FUSE_BN) {
        load_a_regs(t + 1);                              // 4 asm loads (oldest)
        stage_half(Bt, n0, t + 1, Bsn);                  // 2 DMA
        asm volatile("s_waitcnt vmcnt(6)" ::: "memory"); // drain B(t) 4 DMA
      } else {
        stage_half(A,  m0, t + 1, Asn);
        stage_half(Bt, n0, t + 1, Bsn);
        asm volatile("s_waitcnt vmcnt(4)" ::: "memory"); // drain tile t's 8
      }
    } else {
      asm volatile("s_waitcnt vmcnt(0)" ::: "memory");   // last tile drains
    }
    __builtin_amdgcn_sched_barrier(0);
    __builtin_amdgcn_s_barrier();
#pragma unroll
    for (int mf = 0; mf < 4; ++mf)
#pragma unroll
      for (int ks = 0; ks < 2; ++ks)
        aA[mf][ks] = *(const bf16x8*)(Ab + (mf * 16 + l16) * 64 +
                                      ((ks * 32 + quad * 8) ^ swz));
#pragma unroll
    for (int nf = 0; nf < 2; ++nf)
#pragma unroll
      for (int ks = 0; ks < 2; ++ks)
        bB[nf][ks] = *(const bf16x8*)(Bb + (brow + nf * 16 + l16) * 64 +
                                      ((ks * 32 + quad * 8) ^ swz));
    __builtin_amdgcn_s_setprio(1);
#pragma unroll
    for (int mf = 0; mf < 4; ++mf)
#pragma unroll
      for (int nf = 0; nf < 2; ++nf)
#pragma unroll
        for (int ks = 0; ks < 2; ++ks)
          acc[mf][nf] = __builtin_amdgcn_mfma_f32_16x16x32_bf16(
              aA[mf][ks], bB[nf][ks], acc[mf][nf], 0, 0, 0);
    __builtin_amdgcn_s_setprio(0);
    __builtin_amdgcn_s_barrier();

    // ========== phase 1 : (m-half 0) x (n-frags 2,3) ==========
    if (t + 1 < NT) {
      stage_half(Bt, n0 + 128, t + 1, Bsn + 8192);       // 2 DMA
      if constexpr (!FUSE_BN)
        stage_half(A, m0 + 128, t + 1, Asn + 8192);
    }
#pragma unroll
    for (int nf = 2; nf < 4; ++nf)
#pragma unroll
      for (int ks = 0; ks < 2; ++ks)
        bB[nf][ks] = *(const bf16x8*)(Bb + (brow + nf * 16 + l16) * 64 +
                                      ((ks * 32 + quad * 8) ^ swz));
    __builtin_amdgcn_s_setprio(1);
#pragma unroll
    for (int mf = 0; mf < 4; ++mf)
#pragma unroll
      for (int nf = 2; nf < 4; ++nf)
#pragma unroll
        for (int ks = 0; ks < 2; ++ks)
          acc[mf][nf] = __builtin_amdgcn_mfma_f32_16x16x32_bf16(
              aA[mf][ks], bB[nf][ks], acc[mf][nf], 0, 0, 0);
    __builtin_amdgcn_s_setprio(0);
    __builtin_amdgcn_s_barrier();

    // ========== phase 2 : (m-half 1) x (n-frags 0,1) ==========
#pragma unroll
    for (int mf = 0; mf < 4; ++mf)
#pragma unroll
      for (int ks = 0; ks < 2; ++ks)
        aA[mf][ks] = *(const bf16x8*)(Ab + (64 + mf * 16 + l16) * 64 +
                                      ((ks * 32 + quad * 8) ^ swz));
    __builtin_amdgcn_s_setprio(1);
#pragma unroll
    for (int mf = 0; mf < 4; ++mf)
#pragma unroll
      for (int nf = 0; nf < 2; ++nf)
#pragma unroll
        for (int ks = 0; ks < 2; ++ks)
          acc[4 + mf][nf] = __builtin_amdgcn_mfma_f32_16x16x32_bf16(
              aA[mf][ks], bB[nf][ks], acc[4 + mf][nf], 0, 0, 0);
    __builtin_amdgcn_s_setprio(0);
    __builtin_amdgcn_s_barrier();

    // ========== phase 3 : (m-half 1) x (n-frags 2,3) ==========
    __builtin_amdgcn_s_setprio(1);
#pragma unroll
    for (int mf = 0; mf < 4; ++mf)
#pragma unroll
      for (int nf = 2; nf < 4; ++nf)
#pragma unroll
        for (int ks = 0; ks < 2; ++ks)
          acc[4 + mf][nf] = __builtin_amdgcn_mfma_f32_16x16x32_bf16(
              aA[mf][ks], bB[nf][ks], acc[4 + mf][nf], 0, 0, 0);
    __builtin_amdgcn_s_setprio(0);
    if constexpr (FUSE_BN) {
      if (t + 1 < NT) {
        asm volatile("s_waitcnt vmcnt(4)" ::: "memory"); // drain A(t+1) regs
        __builtin_amdgcn_sched_barrier(0);
        bn_write_A(t + 1, Asn);
        asm volatile("s_waitcnt lgkmcnt(0)" ::: "memory");
        __builtin_amdgcn_sched_barrier(0);
      }
    }
    __builtin_amdgcn_s_barrier();
  }

  // ---- epilogue: stats (regs) + C repack through dead As/Bs ---------------
  // C/D layout (m89/m91): n = l16, m = quad*4 + r.
  // LDS repack: bf16 C[256][256]; rows<128 in As, rows>=128 in Bs; columns
  // quad-XOR swizzled (col ^ (quad<<4)) -> conflict-free b16 writes.
  float sArr[4], ssArr[4];
  {
    __bf16* cbase = wm ? Bs : As;
#pragma unroll
    for (int nf = 0; nf < 4; ++nf) {
      const int cl = wn * 64 + nf * 16 + l16;            // block-local col
      const float bv = bias[n0 + cl];
      float s = 0.f, ss = 0.f;
#pragma unroll
      for (int mf = 0; mf < 8; ++mf) {
        const int rl = (wm * 128 + mf * 16 + quad * 4) & 127;
#pragma unroll
        for (int r = 0; r < 4; ++r) {
          const float v = acc[mf][nf][r] + bv;
          s += v; ss += v * v;
          cbase[(rl + r) * 256 + (cl ^ (quad << 4))] = (__bf16)v;
        }
      }
      s  += __shfl_down(s, 32);  s  += __shfl_down(s, 16);
      ss += __shfl_down(ss, 32); ss += __shfl_down(ss, 16);
      sArr[nf] = s; ssArr[nf] = ss;
    }
  }
  if (wm == 1 && quad == 0) {
#pragma unroll
    for (int nf = 0; nf < 4; ++nf) {
      s_red[wn][nf][l16][0] = sArr[nf];
      s_red[wn][nf][l16][1] = ssArr[nf];
    }
  }
  __syncthreads();

  // coalesced C store: 16 passes x 512 thr x 16B = 256x256 bf16
#pragma unroll
  for (int p = 0; p < 16; ++p) {
    const int i   = p * 512 + tid;
    const int row = i >> 5;                 // 0..255
    const int cc  = (i & 31) * 8;           // elem col base
    const __bf16* base = (p < 8) ? As : Bs;
    bf16x8 v = *(const bf16x8*)&base[(row & 127) * 256 +
                                     (cc ^ (((row >> 2) & 3) << 4))];
    *(bf16x8*)&Cout[(size_t)(m0 + row) * 512 + n0 + cc] = v;
  }

  if (wm == 0 && quad == 0) {
    float* rowp = part1 + (size_t)mt * 1024;
#pragma unroll
    for (int nf = 0; nf < 4; ++nf) {
      const int n = n0 + wn * 64 + nf * 16 + l16;
      rowp[n]       = sArr[nf]  + s_red[wn][nf][l16][0];
      rowp[512 + n] = ssArr[nf] + s_red[wn][nf][l16][1];
    }
  }
}

// ---------------------------------------------------------------------------
// Stage A: fold part1[256][1024] -> part2[16][1024] (coalesced)
// ---------------------------------------------------------------------------
__global__ __launch_bounds__(256) void reduce_partials(
    const float* __restrict__ part1, float* __restrict__ part2) {
  const int rb = blockIdx.x;            // 16 blocks, 16 rows each
  const int t  = threadIdx.x;
#pragma unroll
  for (int k = 0; k < 4; ++k) {
    const int c = k * 256 + t;
    float acc = 0.f;
    const float* p = part1 + (size_t)rb * 16 * 1024 + c;
#pragma unroll
    for (int r = 0; r < 16; ++r) { acc += *p; p += 1024; }
    part2[rb * 1024 + c] = acc;
  }
}

// ab layout: [0,512) = scale a, [512,1024) = shift b:  y = a*h + b
__global__ void finalize_stats(const float* __restrict__ part2,
                               const float* __restrict__ g,
                               const float* __restrict__ be,
                               float* __restrict__ ab, float invM) {
  const int c = blockIdx.x * 256 + threadIdx.x;
  if (c < 512) {
    float s = 0.f, ss = 0.f;
#pragma unroll
    for (int r = 0; r < 16; ++r) {
      s  += part2[r * 1024 + c];
      ss += part2[r * 1024 + 512 + c];
    }
    float mean = s * invM;
    float var  = ss * invM - mean * mean;
    float a = g[c] * rsqrtf(var + BN_EPS);
    ab[c] = a;
    ab[512 + c] = be[c] - mean * a;
  }
}

// ---------------------------------------------------------------------------
// BN+ReLU: read bf16 h2, write f32 out (8 elems/thread)
// ---------------------------------------------------------------------------
__global__ __launch_bounds__(256) void bnrelu_b2f(
    const __bf16* __restrict__ H, const float* __restrict__ ab,
    float* __restrict__ O) {
  const size_t e = ((size_t)blockIdx.x * 256 + threadIdx.x) * 8;
  const int c = (int)(e & 511);
  bf16x8 h = *(const bf16x8*)(H + e);
  float4 o0, o1;
  o0.x = fmaxf(fmaf((float)h[0], ab[c + 0], ab[512 + c + 0]), 0.f);
  o0.y = fmaxf(fmaf((float)h[1], ab[c + 1], ab[512 + c + 1]), 0.f);
  o0.z = fmaxf(fmaf((float)h[2], ab[c + 2], ab[512 + c + 2]), 0.f);
  o0.w = fmaxf(fmaf((float)h[3], ab[c + 3], ab[512 + c + 3]), 0.f);
  o1.x = fmaxf(fmaf((float)h[4], ab[c + 4], ab[512 + c + 4]), 0.f);
  o1.y = fmaxf(fmaf((float)h[5], ab[c + 5], ab[512 + c + 5]), 0.f);
  o1.z = fmaxf(fmaf((float)h[6], ab[c + 6], ab[512 + c + 6]), 0.f);
  o1.w = fmaxf(fmaf((float)h[7], ab[c + 7], ab[512 + c + 7]), 0.f);
  *(float4*)(O + e)     = o0;
  *(float4*)(O + e + 4) = o1;
}

// ---------------------------------------------------------------------------
// Tail: pos_skip copy + batch ids as float
// ---------------------------------------------------------------------------
__global__ __launch_bounds__(256) void tail_kernel(
    const float* __restrict__ pos_skip, float* __restrict__ out2) {
  const int i = blockIdx.x * 256 + threadIdx.x;   // 0 .. 262143
  if (i < NF_TOT * 3) {
    out2[i] = pos_skip[i];
  } else {
    const int f = i - NF_TOT * 3;
    out2[i] = (float)(f >> 12);                   // f / NF_PER
  }
}

// ---------------------------------------------------------------------------
// Launch
// ---------------------------------------------------------------------------
extern "C" void kernel_launch(void* const* d_in, const int* in_sizes, int n_in,
                              void* d_out, int out_size, void* d_ws, size_t ws_size,
                              hipStream_t stream) {
  (void)in_sizes; (void)n_in; (void)out_size; (void)ws_size;

  const float* x        = (const float*)d_in[0];
  const float* pos      = (const float*)d_in[1];
  const float* x_skip   = (const float*)d_in[3];
  const float* pos_skip = (const float*)d_in[4];
  const float* W1  = (const float*)d_in[6];
  const float* b1  = (const float*)d_in[7];
  const float* g1  = (const float*)d_in[8];
  const float* be1 = (const float*)d_in[9];
  const float* W2  = (const float*)d_in[10];
  const float* b2  = (const float*)d_in[11];
  const float* g2  = (const float*)d_in[12];
  const float* be2 = (const float*)d_in[13];
  float* out = (float*)d_out;

  char* ws = (char*)d_ws;
  // workspace layout (bytes). h2 aliases h0 (h0 dead after gemm1).
  // part1 reuses the idx3/w3 region (dead after gather_interp).
  __bf16* h0   = (__bf16*)(ws);                          // 100,663,296  h0 [65536,768]
  __bf16* h2   = (__bf16*)(ws);                          //  67,108,864  h2 [65536,512]
  __bf16* h1   = (__bf16*)(ws + 100663296ull);           //  67,108,864  h1 [65536,512] (RAW gemm1 out)
  __bf16* W1t  = (__bf16*)(ws + 167772160ull);           //     786,432  [512,768]
  __bf16* W2t  = (__bf16*)(ws + 168558592ull);           //     524,288  [512,512]
  float*  ab1   = (float*)(ws + 169086976ull);           //       4,096
  float*  ab2   = (float*)(ws + 169095168ull);           //       4,096
  int4*   idx3  = (int4*)(ws + 169099264ull);            //   1,048,576  [65536]
  float4* w3    = (float4*)(ws + 170147840ull);          //   1,048,576  [65536]
  float*  part1 = (float*)(ws + 169099264ull);           //   1,048,576  aliases idx3
  float*  part2 = (float*)(ws + 171196416ull);           //      65,536  [16][1024]

  // weights -> transposed bf16 (both in one kernel)
  transpose_both<<<(D_IN * C_OUT + C_OUT * C_OUT + 255) / 256, 256, 0, stream>>>(
      W1, W2, W1t, W2t);

  // knn (segmented) then gather+concat -> h0
  knn_kernel<<<NF_TOT / 64, 256, 0, stream>>>(pos, pos_skip, idx3, w3);
  gather_interp<<<NF_TOT / 4, 256, 0, stream>>>(x, x_skip, idx3, w3, h0);

  // layer 1: gemm (+fused partial stats) -> reduce -> bn coeffs
  gemm_bt<D_IN, false><<<512, 512, 0, stream>>>(h0, W1t, b1, h1, part1, nullptr);
  reduce_partials<<<16, 256, 0, stream>>>(part1, part2);
  finalize_stats<<<2, 256, 0, stream>>>(part2, g1, be1, ab1, 1.0f / (float)NF_TOT);

  // layer 2: gemm with BN1+ReLU fused into A-staging -> bf16 h2 (+stats)
  gemm_bt<C_OUT, true><<<512, 512, 0, stream>>>(h1, W2t, b2, h2, part1, ab1);
  reduce_partials<<<16, 256, 0, stream>>>(part1, part2);
  finalize_stats<<<2, 256, 0, stream>>>(part2, g2, be2, ab2, 1.0f / (float)NF_TOT);
  bnrelu_b2f<<<(NF_TOT * 512 / 8) / 256, 256, 0, stream>>>(h2, ab2, out);

  // pos_skip + batch_skip outputs
  tail_kernel<<<(NF_TOT * 3 + NF_TOT + 255) / 256, 256, 0, stream>>>(
      pos_skip, out + (size_t)NF_TOT * 512);
}